// Round 1
// 323.000 us; speedup vs baseline: 1.0338x; 1.0338x over previous
//
#include <hip/hip_runtime.h>

// GCNLinkPredictor: 2-layer GCN, N=100000, E=3.2M, F=128, U=1000.
// R8: latency-attack round.
//  (a) fill_csr: 4 edges/thread via int4 loads of src/dst, 4 concurrent
//      frB gathers + 4 in-flight atomics (was 1 edge/thread, ILP=1,
//      56us @ 17% HBM / 2% VALU -> pure latency bound).
//  (b) frB: byte frontier flags (100KB vs 400KB) written by reduce_prep;
//      4x L2 line density for the 3.2M random flag reads in fill_csr.
//  (c) hist: int4 dst scan (9 iters/block instead of 37) for 4x MLP.
//  (d) passthrough memcpy fused into gemm_f16 staging loop (gemm already
//      reads every x row as float4; store rows >= U to out directly),
//      eliminating a 50.7MB re-read + one launch.
//  (e) gather_l2: 4-edge unrolled inner loop (250-block kernel was fully
//      serial per edge).

#define F_DIM 128
#define U_USERS 1000
#define SCAN_CHUNK 1024
#define NFCAP 48000     // frontier cap (expected ~33K)
#define NCHUNK 3        // node-space chunks for histogram
#define SBIN 40960      // nodes per chunk (3*40960 >= 100000)
#define SW (SBIN / 2)   // packed words per chunk (2 x u16 per word)
#define PSLICE 85       // edge slices per chunk -> 255 blocks
#define XPAD 136        // fp16 LDS row stride (128 + 8)

using f16x8 = __attribute__((ext_vector_type(8))) _Float16;
using f16x2 = __attribute__((ext_vector_type(2))) _Float16;
using f32x4 = __attribute__((ext_vector_type(4))) float;

union H4 { uint2 u2; _Float16 h[4]; };

// ---- histogram: LDS packed counters, no global atomics ----
__global__ __launch_bounds__(1024) void hist_kernel(const int* __restrict__ src,
                                                    const int* __restrict__ dst,
                                                    unsigned int* __restrict__ partial,
                                                    int* __restrict__ fr, int E, int n) {
    __shared__ unsigned int h[SW];   // 80 KB
    int tid = threadIdx.x;
    int c = blockIdx.x % NCHUNK;
    int p = blockIdx.x / NCHUNK;
    for (int i = tid; i < SW; i += 1024) h[i] = 0u;
    __syncthreads();

    int lo = c * SBIN;
    int hi = lo + SBIN;
    int len = (E + PSLICE - 1) / PSLICE;
    int base = p * len;
    int end = min(E, base + len);
    // vectorized: 4 edges per thread per iteration (slice bounds are
    // multiples of 4 for E=3.2M/PSLICE=85, but guard the tail anyway)
    int e = base + tid * 4;
    for (; e + 3 < end; e += 4096) {
        int4 dv = *(const int4*)(dst + e);
#pragma unroll
        for (int i = 0; i < 4; ++i) {
            int d = ((const int*)&dv)[i];
            if ((unsigned)d < (unsigned)n) {
                if (d >= lo && d < hi) {
                    int local = d - lo;
                    atomicAdd(&h[local >> 1], 1u << ((local & 1) << 4));
                }
                if (c == 0 && d < U_USERS) {
                    int s = src[e + i];
                    if ((unsigned)s < (unsigned)n) fr[s] = 1;
                }
            }
        }
    }
    for (; e < end; ++e) {   // tail (rare)
        int d = dst[e];
        if ((unsigned)d < (unsigned)n) {
            if (d >= lo && d < hi) {
                int local = d - lo;
                atomicAdd(&h[local >> 1], 1u << ((local & 1) << 4));
            }
            if (c == 0 && d < U_USERS) {
                int s = src[e];
                if ((unsigned)s < (unsigned)n) fr[s] = 1;
            }
        }
    }
    __syncthreads();
    unsigned int* outp = partial + ((size_t)(c * PSLICE + p)) * SW;
    for (int i = tid; i < SW; i += 1024) outp[i] = h[i];
}

// ---- reduce partials -> deg; fused prep: inv, degF, fr[i<U]=1, frB ----
__global__ void reduce_prep_kernel(const unsigned int* __restrict__ partial,
                                   float* __restrict__ inv, int* __restrict__ fr,
                                   int* __restrict__ degF,
                                   unsigned char* __restrict__ frB, int n) {
    int t = blockIdx.x * blockDim.x + threadIdx.x;
    if (t >= NCHUNK * SW) return;
    int c = t / SW, w = t % SW;
    unsigned int a0 = 0, a1 = 0;
    const unsigned int* basep = partial + (size_t)c * PSLICE * SW + w;
#pragma unroll 5
    for (int p = 0; p < PSLICE; ++p) {
        unsigned int v = basep[(size_t)p * SW];
        a0 += v & 0xFFFFu;
        a1 += v >> 16;
    }
    int i0 = c * SBIN + 2 * w;
#pragma unroll
    for (int k = 0; k < 2; ++k) {
        int i = i0 + k;
        unsigned int dg = k ? a1 : a0;
        if (i < n) {
            inv[i] = rsqrtf((float)dg + 1.0f);
            bool isfr = (i < U_USERS) || (fr[i] != 0);
            if (i < U_USERS) fr[i] = 1;
            degF[i] = isfr ? (int)dg : 0;
            frB[i] = isfr ? (unsigned char)1 : (unsigned char)0;
        }
    }
}

// ---- dual exclusive scan (degF -> rp, fr -> remap), 3 kernels ----
__global__ void scan_reduce2_kernel(const int* __restrict__ dA, const int* __restrict__ dB,
                                    int* __restrict__ pA, int* __restrict__ pB, int n) {
    __shared__ int sdata[256];
    int b = blockIdx.x, t = threadIdx.x;
    int base = b * SCAN_CHUNK;
    int sumA = 0, sumB = 0;
#pragma unroll
    for (int i = 0; i < 4; ++i) {
        int idx = base + t + 256 * i;
        if (idx < n) { sumA += dA[idx]; sumB += dB[idx]; }
    }
    sdata[t] = sumA; __syncthreads();
    for (int s = 128; s > 0; s >>= 1) { if (t < s) sdata[t] += sdata[t + s]; __syncthreads(); }
    if (t == 0) pA[b] = sdata[0];
    __syncthreads();
    sdata[t] = sumB; __syncthreads();
    for (int s = 128; s > 0; s >>= 1) { if (t < s) sdata[t] += sdata[t + s]; __syncthreads(); }
    if (t == 0) pB[b] = sdata[0];
}

__global__ void scan_partials2_kernel(int* __restrict__ pA, int* __restrict__ pB, int nb) {
    int t = threadIdx.x;
    if (t == 0)  { int run = 0; for (int i = 0; i < nb; ++i) { int v = pA[i]; pA[i] = run; run += v; } }
    if (t == 64) { int run = 0; for (int i = 0; i < nb; ++i) { int v = pB[i]; pB[i] = run; run += v; } }
}

__global__ void scan_final2_kernel(const int* __restrict__ dA, const int* __restrict__ pA,
                                   int* __restrict__ rp,
                                   const int* __restrict__ dB, const int* __restrict__ pB,
                                   int* __restrict__ remap,
                                   int* __restrict__ flist, int* __restrict__ nf_dev, int n) {
    __shared__ int sthread[256];
    int b = blockIdx.x, t = threadIdx.x;
    int base = b * SCAN_CHUNK;
    {
        int v[4]; int sum = 0;
#pragma unroll
        for (int i = 0; i < 4; ++i) { int idx = base + 4 * t + i; v[i] = (idx < n) ? dA[idx] : 0; sum += v[i]; }
        sthread[t] = sum; __syncthreads();
        for (int ofs = 1; ofs < 256; ofs <<= 1) {
            int val = (t >= ofs) ? sthread[t - ofs] : 0;
            __syncthreads(); sthread[t] += val; __syncthreads();
        }
        int run = sthread[t] - sum + pA[b];
#pragma unroll
        for (int i = 0; i < 4; ++i) { int idx = base + 4 * t + i; if (idx < n) rp[idx] = run; run += v[i]; }
        __syncthreads();
    }
    {
        int v[4]; int sum = 0;
#pragma unroll
        for (int i = 0; i < 4; ++i) { int idx = base + 4 * t + i; v[i] = (idx < n) ? dB[idx] : 0; sum += v[i]; }
        sthread[t] = sum; __syncthreads();
        for (int ofs = 1; ofs < 256; ofs <<= 1) {
            int val = (t >= ofs) ? sthread[t - ofs] : 0;
            __syncthreads(); sthread[t] += val; __syncthreads();
        }
        int run = sthread[t] - sum + pB[b];
#pragma unroll
        for (int i = 0; i < 4; ++i) {
            int idx = base + 4 * t + i;
            if (idx < n) {
                remap[idx] = run;
                if (v[i] && run < NFCAP) flist[run] = idx;
                if (idx == n - 1) *nf_dev = min(run + v[i], NFCAP);
            }
            run += v[i];
        }
    }
}

// ---- CSR fill (frontier rows only): 4 edges/thread for MLP ----
__global__ __launch_bounds__(256) void fill_csr_kernel(const int* __restrict__ src,
                                                       const int* __restrict__ dst,
                                                       const unsigned char* __restrict__ frB,
                                                       int* __restrict__ rp, int* __restrict__ col,
                                                       int E, int n) {
    int t = blockIdx.x * blockDim.x + threadIdx.x;
    int e0 = t * 4;
    if (e0 + 3 < E) {
        int4 dv = *(const int4*)(dst + e0);
        int4 sv = *(const int4*)(src + e0);
        const int* dp = (const int*)&dv;
        const int* sp = (const int*)&sv;
        // issue all 4 random flag gathers first (independent, overlap latency)
        unsigned char f[4];
#pragma unroll
        for (int i = 0; i < 4; ++i) {
            int d = dp[i];
            f[i] = ((unsigned)d < (unsigned)n) ? frB[d] : (unsigned char)0;
        }
        // 4 independent atomic+store chains
#pragma unroll
        for (int i = 0; i < 4; ++i) {
            if (f[i]) {
                int d = dp[i], s = sp[i];
                if ((unsigned)s < (unsigned)n) {
                    int pos = atomicAdd(&rp[d], 1);
                    if ((unsigned)pos < (unsigned)E) col[pos] = s;
                }
            }
        }
    } else {
        for (int e = e0; e < E; ++e) {
            int d = dst[e], s = src[e];
            if ((unsigned)d < (unsigned)n && (unsigned)s < (unsigned)n && frB[d]) {
                int pos = atomicAdd(&rp[d], 1);
                if ((unsigned)pos < (unsigned)E) col[pos] = s;
            }
        }
    }
}

// ---- MFMA fp16 GEMM: outh[n,128] = f16(X[n,128] @ W[128,128]) ----
// 256 threads = 4 waves, 64 rows/block. LDS: Xs fp16 [64][136] (17KB) +
// Wt fp16 (W transposed, [n][k]) [128][136] (34KB) -> 3 blocks/CU.
// Wave w: rows [16w,16w+16), all 128 cols (8 col-tiles), K=128 in 4 chunks.
// pout != nullptr: also store raw x rows >= U to out (fused passthrough).
__device__ __forceinline__ void gemm_mfma_body(const float* __restrict__ X,
                                               const float* __restrict__ W,
                                               _Float16* __restrict__ outh,
                                               float* __restrict__ pout,
                                               int nrows, int rowBase) {
    __shared__ _Float16 Wt[128 * XPAD];   // [n][k]
    __shared__ _Float16 Xs[64 * XPAD];    // [r][k]

    int tid = threadIdx.x;

    // stage W transposed: 4096 float4s / 256 threads = 16 each
    const float4* W4 = (const float4*)W;
#pragma unroll
    for (int i = 0; i < 16; ++i) {
        int j = tid + 256 * i;        // j = k*32 + n4
        int k = j >> 5;
        int n4 = j & 31;
        float4 v = W4[j];
#pragma unroll
        for (int q = 0; q < 4; ++q)
            Wt[(n4 * 4 + q) * XPAD + k] = (_Float16)((const float*)&v)[q];
    }

    // stage X tile fp16 row-major: 2048 float4s / 256 = 8 each
#pragma unroll
    for (int i = 0; i < 8; ++i) {
        int j = tid + 256 * i;        // j = r*32 + k4
        int r = j >> 5;
        int k4 = j & 31;
        int row = rowBase + r;
        float4 v = make_float4(0.f, 0.f, 0.f, 0.f);
        if (row < nrows) {
            v = ((const float4*)(X + (size_t)row * F_DIM))[k4];
            if (pout != nullptr && row >= U_USERS)
                ((float4*)(pout + (size_t)row * F_DIM))[k4] = v;   // fused passthrough
        }
        H4 p;
#pragma unroll
        for (int q = 0; q < 4; ++q) p.h[q] = (_Float16)((const float*)&v)[q];
        *(uint2*)&Xs[r * XPAD + k4 * 4] = p.u2;
    }
    __syncthreads();

    int w = tid >> 6;
    int lane = tid & 63;
    int m = lane & 15;
    int quad = lane >> 4;
    int R = w * 16;                   // block-local row base for this wave

    f32x4 acc[8];
#pragma unroll
    for (int i = 0; i < 8; ++i) acc[i] = (f32x4){0.f, 0.f, 0.f, 0.f};

#pragma unroll
    for (int kc = 0; kc < 4; ++kc) {
        f16x8 a = *(const f16x8*)&Xs[(R + m) * XPAD + kc * 32 + quad * 8];
#pragma unroll
        for (int ct = 0; ct < 8; ++ct) {
            f16x8 b = *(const f16x8*)&Wt[(ct * 16 + m) * XPAD + kc * 32 + quad * 8];
            acc[ct] = __builtin_amdgcn_mfma_f32_16x16x32_f16(a, b, acc[ct], 0, 0, 0);
        }
    }

#pragma unroll
    for (int ct = 0; ct < 8; ++ct) {
#pragma unroll
        for (int reg = 0; reg < 4; ++reg) {
            int row = rowBase + R + quad * 4 + reg;
            if (row < nrows)
                outh[(size_t)row * F_DIM + ct * 16 + m] = (_Float16)acc[ct][reg];
        }
    }
}

__global__ __launch_bounds__(256) void gemm_f16_kernel(const float* __restrict__ X,
                                                       const float* __restrict__ W,
                                                       _Float16* __restrict__ outh,
                                                       float* __restrict__ pout, int nrows) {
    gemm_mfma_body(X, W, outh, pout, nrows, blockIdx.x * 64);
}

__global__ __launch_bounds__(256) void gemm_f16_dyn_kernel(const float* __restrict__ X,
                                                           const float* __restrict__ W,
                                                           _Float16* __restrict__ outh,
                                                           const int* __restrict__ nrows_p) {
    int nrows = *nrows_p;
    int rowBase = blockIdx.x * 64;
    if (rowBase >= nrows) return;
    gemm_mfma_body(X, W, outh, nullptr, nrows, rowBase);
}

// ---- layer-1 gather over compact frontier rows (fp16 rows, fp32 accum) ----
__global__ __launch_bounds__(256) void gather_l1_kernel(const _Float16* __restrict__ xwh,
                                                        const float* __restrict__ inv,
                                                        const int* __restrict__ rp,
                                                        const int* __restrict__ col,
                                                        const int* __restrict__ flist,
                                                        const int* __restrict__ nf_p,
                                                        const float* __restrict__ b,
                                                        float* __restrict__ h1c) {
    int ci = blockIdx.x * 4 + (threadIdx.x >> 6);
    if (ci >= *nf_p) return;
    int lane = threadIdx.x & 63;
    int node = flist[ci];
    int start = (node == 0) ? 0 : rp[node - 1];
    int end = rp[node];

    float accx = 0.f, accy = 0.f;
    for (int base = start; base < end; base += 64) {
        int j = base + lane;
        int s_l = 0; float c_l = 0.f;
        if (j < end) { s_l = col[j]; c_l = inv[s_l]; }
        int cnt = min(64, end - base);
        int i = 0;
        for (; i + 4 <= cnt; i += 4) {
            int s0 = __shfl(s_l, i + 0); float f0 = __shfl(c_l, i + 0);
            int s1 = __shfl(s_l, i + 1); float f1 = __shfl(c_l, i + 1);
            int s2 = __shfl(s_l, i + 2); float f2 = __shfl(c_l, i + 2);
            int s3 = __shfl(s_l, i + 3); float f3 = __shfl(c_l, i + 3);
            f16x2 v0 = ((const f16x2*)(xwh + (size_t)s0 * F_DIM))[lane];
            f16x2 v1 = ((const f16x2*)(xwh + (size_t)s1 * F_DIM))[lane];
            f16x2 v2 = ((const f16x2*)(xwh + (size_t)s2 * F_DIM))[lane];
            f16x2 v3 = ((const f16x2*)(xwh + (size_t)s3 * F_DIM))[lane];
            accx += (float)v0[0] * f0 + (float)v1[0] * f1 + (float)v2[0] * f2 + (float)v3[0] * f3;
            accy += (float)v0[1] * f0 + (float)v1[1] * f1 + (float)v2[1] * f2 + (float)v3[1] * f3;
        }
        for (; i < cnt; ++i) {
            int s0 = __shfl(s_l, i); float f0 = __shfl(c_l, i);
            f16x2 v0 = ((const f16x2*)(xwh + (size_t)s0 * F_DIM))[lane];
            accx += (float)v0[0] * f0;
            accy += (float)v0[1] * f0;
        }
    }

    float ivd = inv[node];
    f16x2 self = ((const f16x2*)(xwh + (size_t)node * F_DIM))[lane];
    float vx = accx * ivd + (float)self[0] * ivd * ivd + b[lane * 2];
    float vy = accy * ivd + (float)self[1] * ivd * ivd + b[lane * 2 + 1];
    vx = vx > 0.f ? vx : expf(vx) - 1.f;
    vy = vy > 0.f ? vy : expf(vy) - 1.f;
    ((float2*)(h1c + (size_t)ci * F_DIM))[lane] = make_float2(vx, vy);
}

// ---- layer-2 gather over rows [0,U) (fp16 compact rows) ----
__global__ __launch_bounds__(256) void gather_l2_kernel(const _Float16* __restrict__ xwc,
                                                        const float* __restrict__ inv,
                                                        const int* __restrict__ rp,
                                                        const int* __restrict__ col,
                                                        const int* __restrict__ remap,
                                                        const float* __restrict__ b,
                                                        float* __restrict__ out) {
    int node = blockIdx.x * 4 + (threadIdx.x >> 6);
    if (node >= U_USERS) return;
    int lane = threadIdx.x & 63;
    int start = (node == 0) ? 0 : rp[node - 1];
    int end = rp[node];

    float accx = 0.f, accy = 0.f;
    for (int base = start; base < end; base += 64) {
        int j = base + lane;
        int r_l = 0; float c_l = 0.f;
        if (j < end) { int s = col[j]; c_l = inv[s]; r_l = remap[s]; }
        int cnt = min(64, end - base);
        int i = 0;
        for (; i + 4 <= cnt; i += 4) {
            int r0 = __shfl(r_l, i + 0); float f0 = __shfl(c_l, i + 0);
            int r1 = __shfl(r_l, i + 1); float f1 = __shfl(c_l, i + 1);
            int r2 = __shfl(r_l, i + 2); float f2 = __shfl(c_l, i + 2);
            int r3 = __shfl(r_l, i + 3); float f3 = __shfl(c_l, i + 3);
            f16x2 v0 = ((const f16x2*)(xwc + (size_t)r0 * F_DIM))[lane];
            f16x2 v1 = ((const f16x2*)(xwc + (size_t)r1 * F_DIM))[lane];
            f16x2 v2 = ((const f16x2*)(xwc + (size_t)r2 * F_DIM))[lane];
            f16x2 v3 = ((const f16x2*)(xwc + (size_t)r3 * F_DIM))[lane];
            accx += (float)v0[0] * f0 + (float)v1[0] * f1 + (float)v2[0] * f2 + (float)v3[0] * f3;
            accy += (float)v0[1] * f0 + (float)v1[1] * f1 + (float)v2[1] * f2 + (float)v3[1] * f3;
        }
        for (; i < cnt; ++i) {
            int rr = __shfl(r_l, i); float f0 = __shfl(c_l, i);
            f16x2 v0 = ((const f16x2*)(xwc + (size_t)rr * F_DIM))[lane];
            accx += (float)v0[0] * f0;
            accy += (float)v0[1] * f0;
        }
    }

    float ivd = inv[node];
    f16x2 self = ((const f16x2*)(xwc + (size_t)node * F_DIM))[lane];  // remap[node]==node for node<U
    float vx = accx * ivd + (float)self[0] * ivd * ivd + b[lane * 2];
    float vy = accy * ivd + (float)self[1] * ivd * ivd + b[lane * 2 + 1];
    vx = vx > 0.f ? vx : expf(vx) - 1.f;
    vy = vy > 0.f ? vy : expf(vy) - 1.f;
    ((float2*)(out + (size_t)node * F_DIM))[lane] = make_float2(vx, vy);
}

extern "C" void kernel_launch(void* const* d_in, const int* in_sizes, int n_in,
                              void* d_out, int out_size, void* d_ws, size_t ws_size,
                              hipStream_t stream) {
    const float* x  = (const float*)d_in[0];
    const int*   ei = (const int*)d_in[1];   // [2, E] int32
    const float* W1 = (const float*)d_in[2];
    const float* b1 = (const float*)d_in[3];
    const float* W2 = (const float*)d_in[4];
    const float* b2 = (const float*)d_in[5];
    float* out = (float*)d_out;

    int n = in_sizes[0] / F_DIM;   // 100000
    int E = in_sizes[1] / 2;       // 3200000
    const int* srcI = ei;
    const int* dstI = ei + E;

    // workspace layout (~110 MB)
    _Float16* xwh = (_Float16*)d_ws;                 // n*128 halfs (xw1 / xwc, 25.6MB)
    float* h1c   = (float*)(xwh + (size_t)n * F_DIM);// NFCAP*128 f (24.6MB)
    float* inv   = h1c + (size_t)NFCAP * F_DIM;      // n f
    int* fr      = (int*)(inv + n);                  // n
    int* degF    = fr + n;                           // n
    int* remap   = degF + n;                         // n
    int* rp      = remap + n;                        // n
    int* flist   = rp + n;                           // NFCAP
    int* pA      = flist + NFCAP;                    // 1024
    int* pB      = pA + 1024;                        // 1024
    int* nf_dev  = pB + 1024;                        // 1 (+pad)
    int* col     = nf_dev + 16;                      // E
    unsigned int* partialH = (unsigned int*)(col + E);  // NCHUNK*PSLICE*SW
    unsigned char* frB = (unsigned char*)(partialH + (size_t)NCHUNK * PSLICE * SW); // n bytes

    int nb = (n + SCAN_CHUNK - 1) / SCAN_CHUNK;      // 98

    hipMemsetAsync(fr, 0, (size_t)n * sizeof(int), stream);

    hist_kernel<<<NCHUNK * PSLICE, 1024, 0, stream>>>(srcI, dstI, partialH, fr, E, n);
    reduce_prep_kernel<<<(NCHUNK * SW + 255) / 256, 256, 0, stream>>>(partialH, inv, fr, degF, frB, n);

    scan_reduce2_kernel<<<nb, 256, 0, stream>>>(degF, fr, pA, pB, n);
    scan_partials2_kernel<<<1, 128, 0, stream>>>(pA, pB, nb);
    scan_final2_kernel<<<nb, 256, 0, stream>>>(degF, pA, rp, fr, pB, remap, flist, nf_dev, n);

    fill_csr_kernel<<<(E / 4 + 255) / 256, 256, 0, stream>>>(srcI, dstI, frB, rp, col, E, n);

    // layer 1: full MFMA GEMM (fp16 out) + fused passthrough, frontier-only gather
    gemm_f16_kernel<<<(n + 63) / 64, 256, 0, stream>>>(x, W1, xwh, out, n);
    gather_l1_kernel<<<(NFCAP + 3) / 4, 256, 0, stream>>>(xwh, inv, rp, col, flist, nf_dev, b1, h1c);

    // layer 2: compact MFMA GEMM (nf rows), gather over U rows
    gemm_f16_dyn_kernel<<<(NFCAP + 63) / 64, 256, 0, stream>>>(h1c, W2, xwh, nf_dev);
    gather_l2_kernel<<<(U_USERS + 3) / 4, 256, 0, stream>>>(xwh, inv, rp, col, remap, b2, out);
}

// Round 2
// 314.566 us; speedup vs baseline: 1.0615x; 1.0268x over previous
//
#include <hip/hip_runtime.h>

// GCNLinkPredictor: 2-layer GCN, N=100000, E=3.2M, F=128, U=1000.
// R9: fill_csr split-phase MLP fix.
//   R8 regression root-cause: atomicAdd + dependent store in the SAME
//   divergent branch => s_waitcnt vmcnt(0) per branch => 4 serial ~600cy
//   atomic round-trips per thread (worse than 1-edge/thread TLP).
//   Fix: phase-split. (1) 4 independent frB gathers; (2) issue 4
//   atomicAdds into pos[] with no in-branch use (4 in flight);
//   (3) one wait, 4 independent col stores.
// Carried from R8 (all helped, net -22us): frB byte flags, hist int4 scan,
// passthrough fused into gemm staging, gather_l2 4-edge unroll.

#define F_DIM 128
#define U_USERS 1000
#define SCAN_CHUNK 1024
#define NFCAP 48000     // frontier cap (expected ~33K)
#define NCHUNK 3        // node-space chunks for histogram
#define SBIN 40960      // nodes per chunk (3*40960 >= 100000)
#define SW (SBIN / 2)   // packed words per chunk (2 x u16 per word)
#define PSLICE 85       // edge slices per chunk -> 255 blocks
#define XPAD 136        // fp16 LDS row stride (128 + 8)

using f16x8 = __attribute__((ext_vector_type(8))) _Float16;
using f16x2 = __attribute__((ext_vector_type(2))) _Float16;
using f32x4 = __attribute__((ext_vector_type(4))) float;

union H4 { uint2 u2; _Float16 h[4]; };

// ---- histogram: LDS packed counters, no global atomics ----
__global__ __launch_bounds__(1024) void hist_kernel(const int* __restrict__ src,
                                                    const int* __restrict__ dst,
                                                    unsigned int* __restrict__ partial,
                                                    int* __restrict__ fr, int E, int n) {
    __shared__ unsigned int h[SW];   // 80 KB
    int tid = threadIdx.x;
    int c = blockIdx.x % NCHUNK;
    int p = blockIdx.x / NCHUNK;
    for (int i = tid; i < SW; i += 1024) h[i] = 0u;
    __syncthreads();

    int lo = c * SBIN;
    int hi = lo + SBIN;
    int len = (E + PSLICE - 1) / PSLICE;
    int base = p * len;
    int end = min(E, base + len);
    // vectorized: 4 edges per thread per iteration
    int e = base + tid * 4;
    for (; e + 3 < end; e += 4096) {
        int4 dv = *(const int4*)(dst + e);
#pragma unroll
        for (int i = 0; i < 4; ++i) {
            int d = ((const int*)&dv)[i];
            if ((unsigned)d < (unsigned)n) {
                if (d >= lo && d < hi) {
                    int local = d - lo;
                    atomicAdd(&h[local >> 1], 1u << ((local & 1) << 4));
                }
                if (c == 0 && d < U_USERS) {
                    int s = src[e + i];
                    if ((unsigned)s < (unsigned)n) fr[s] = 1;
                }
            }
        }
    }
    for (; e < end; ++e) {   // tail (rare)
        int d = dst[e];
        if ((unsigned)d < (unsigned)n) {
            if (d >= lo && d < hi) {
                int local = d - lo;
                atomicAdd(&h[local >> 1], 1u << ((local & 1) << 4));
            }
            if (c == 0 && d < U_USERS) {
                int s = src[e];
                if ((unsigned)s < (unsigned)n) fr[s] = 1;
            }
        }
    }
    __syncthreads();
    unsigned int* outp = partial + ((size_t)(c * PSLICE + p)) * SW;
    for (int i = tid; i < SW; i += 1024) outp[i] = h[i];
}

// ---- reduce partials -> deg; fused prep: inv, degF, fr[i<U]=1, frB ----
__global__ void reduce_prep_kernel(const unsigned int* __restrict__ partial,
                                   float* __restrict__ inv, int* __restrict__ fr,
                                   int* __restrict__ degF,
                                   unsigned char* __restrict__ frB, int n) {
    int t = blockIdx.x * blockDim.x + threadIdx.x;
    if (t >= NCHUNK * SW) return;
    int c = t / SW, w = t % SW;
    unsigned int a0 = 0, a1 = 0;
    const unsigned int* basep = partial + (size_t)c * PSLICE * SW + w;
#pragma unroll 5
    for (int p = 0; p < PSLICE; ++p) {
        unsigned int v = basep[(size_t)p * SW];
        a0 += v & 0xFFFFu;
        a1 += v >> 16;
    }
    int i0 = c * SBIN + 2 * w;
#pragma unroll
    for (int k = 0; k < 2; ++k) {
        int i = i0 + k;
        unsigned int dg = k ? a1 : a0;
        if (i < n) {
            inv[i] = rsqrtf((float)dg + 1.0f);
            bool isfr = (i < U_USERS) || (fr[i] != 0);
            if (i < U_USERS) fr[i] = 1;
            degF[i] = isfr ? (int)dg : 0;
            frB[i] = isfr ? (unsigned char)1 : (unsigned char)0;
        }
    }
}

// ---- dual exclusive scan (degF -> rp, fr -> remap), 3 kernels ----
__global__ void scan_reduce2_kernel(const int* __restrict__ dA, const int* __restrict__ dB,
                                    int* __restrict__ pA, int* __restrict__ pB, int n) {
    __shared__ int sdata[256];
    int b = blockIdx.x, t = threadIdx.x;
    int base = b * SCAN_CHUNK;
    int sumA = 0, sumB = 0;
#pragma unroll
    for (int i = 0; i < 4; ++i) {
        int idx = base + t + 256 * i;
        if (idx < n) { sumA += dA[idx]; sumB += dB[idx]; }
    }
    sdata[t] = sumA; __syncthreads();
    for (int s = 128; s > 0; s >>= 1) { if (t < s) sdata[t] += sdata[t + s]; __syncthreads(); }
    if (t == 0) pA[b] = sdata[0];
    __syncthreads();
    sdata[t] = sumB; __syncthreads();
    for (int s = 128; s > 0; s >>= 1) { if (t < s) sdata[t] += sdata[t + s]; __syncthreads(); }
    if (t == 0) pB[b] = sdata[0];
}

__global__ void scan_partials2_kernel(int* __restrict__ pA, int* __restrict__ pB, int nb) {
    int t = threadIdx.x;
    if (t == 0)  { int run = 0; for (int i = 0; i < nb; ++i) { int v = pA[i]; pA[i] = run; run += v; } }
    if (t == 64) { int run = 0; for (int i = 0; i < nb; ++i) { int v = pB[i]; pB[i] = run; run += v; } }
}

__global__ void scan_final2_kernel(const int* __restrict__ dA, const int* __restrict__ pA,
                                   int* __restrict__ rp,
                                   const int* __restrict__ dB, const int* __restrict__ pB,
                                   int* __restrict__ remap,
                                   int* __restrict__ flist, int* __restrict__ nf_dev, int n) {
    __shared__ int sthread[256];
    int b = blockIdx.x, t = threadIdx.x;
    int base = b * SCAN_CHUNK;
    {
        int v[4]; int sum = 0;
#pragma unroll
        for (int i = 0; i < 4; ++i) { int idx = base + 4 * t + i; v[i] = (idx < n) ? dA[idx] : 0; sum += v[i]; }
        sthread[t] = sum; __syncthreads();
        for (int ofs = 1; ofs < 256; ofs <<= 1) {
            int val = (t >= ofs) ? sthread[t - ofs] : 0;
            __syncthreads(); sthread[t] += val; __syncthreads();
        }
        int run = sthread[t] - sum + pA[b];
#pragma unroll
        for (int i = 0; i < 4; ++i) { int idx = base + 4 * t + i; if (idx < n) rp[idx] = run; run += v[i]; }
        __syncthreads();
    }
    {
        int v[4]; int sum = 0;
#pragma unroll
        for (int i = 0; i < 4; ++i) { int idx = base + 4 * t + i; v[i] = (idx < n) ? dB[idx] : 0; sum += v[i]; }
        sthread[t] = sum; __syncthreads();
        for (int ofs = 1; ofs < 256; ofs <<= 1) {
            int val = (t >= ofs) ? sthread[t - ofs] : 0;
            __syncthreads(); sthread[t] += val; __syncthreads();
        }
        int run = sthread[t] - sum + pB[b];
#pragma unroll
        for (int i = 0; i < 4; ++i) {
            int idx = base + 4 * t + i;
            if (idx < n) {
                remap[idx] = run;
                if (v[i] && run < NFCAP) flist[run] = idx;
                if (idx == n - 1) *nf_dev = min(run + v[i], NFCAP);
            }
            run += v[i];
        }
    }
}

// ---- CSR fill: 4 edges/thread, SPLIT-PHASE (issue atomics, then stores) ----
__global__ __launch_bounds__(256) void fill_csr_kernel(const int* __restrict__ src,
                                                       const int* __restrict__ dst,
                                                       const unsigned char* __restrict__ frB,
                                                       int* __restrict__ rp, int* __restrict__ col,
                                                       int E, int n) {
    int t = blockIdx.x * blockDim.x + threadIdx.x;
    int e0 = t * 4;
    if (e0 + 3 < E) {
        int4 dv = *(const int4*)(dst + e0);
        int4 sv = *(const int4*)(src + e0);
        const int* dp = (const int*)&dv;
        const int* sp = (const int*)&sv;
        // phase 1: 4 independent flag gathers (100KB table, L1/L2 resident)
        bool f[4];
#pragma unroll
        for (int i = 0; i < 4; ++i) {
            int d = dp[i];
            f[i] = ((unsigned)d < (unsigned)n) && ((unsigned)sp[i] < (unsigned)n)
                   && frB[d] != 0;
        }
        // phase 2: issue all 4 atomics; results NOT consumed here -> no
        // vmcnt wait between them, 4 device-scope atomics in flight.
        int pos[4];
#pragma unroll
        for (int i = 0; i < 4; ++i) {
            pos[i] = -1;
            if (f[i]) pos[i] = atomicAdd(&rp[dp[i]], 1);
        }
        // phase 3: one wait, 4 independent scattered stores
#pragma unroll
        for (int i = 0; i < 4; ++i) {
            if (f[i] && (unsigned)pos[i] < (unsigned)E) col[pos[i]] = sp[i];
        }
    } else {
        for (int e = e0; e < E; ++e) {
            int d = dst[e], s = src[e];
            if ((unsigned)d < (unsigned)n && (unsigned)s < (unsigned)n && frB[d]) {
                int pos = atomicAdd(&rp[d], 1);
                if ((unsigned)pos < (unsigned)E) col[pos] = s;
            }
        }
    }
}

// ---- MFMA fp16 GEMM: outh[n,128] = f16(X[n,128] @ W[128,128]) ----
// 256 threads = 4 waves, 64 rows/block. LDS: Xs fp16 [64][136] (17KB) +
// Wt fp16 (W transposed, [n][k]) [128][136] (34KB) -> 3 blocks/CU.
// Wave w: rows [16w,16w+16), all 128 cols (8 col-tiles), K=128 in 4 chunks.
// pout != nullptr: also store raw x rows >= U to out (fused passthrough).
__device__ __forceinline__ void gemm_mfma_body(const float* __restrict__ X,
                                               const float* __restrict__ W,
                                               _Float16* __restrict__ outh,
                                               float* __restrict__ pout,
                                               int nrows, int rowBase) {
    __shared__ _Float16 Wt[128 * XPAD];   // [n][k]
    __shared__ _Float16 Xs[64 * XPAD];    // [r][k]

    int tid = threadIdx.x;

    // stage W transposed: 4096 float4s / 256 threads = 16 each
    const float4* W4 = (const float4*)W;
#pragma unroll
    for (int i = 0; i < 16; ++i) {
        int j = tid + 256 * i;        // j = k*32 + n4
        int k = j >> 5;
        int n4 = j & 31;
        float4 v = W4[j];
#pragma unroll
        for (int q = 0; q < 4; ++q)
            Wt[(n4 * 4 + q) * XPAD + k] = (_Float16)((const float*)&v)[q];
    }

    // stage X tile fp16 row-major: 2048 float4s / 256 = 8 each
#pragma unroll
    for (int i = 0; i < 8; ++i) {
        int j = tid + 256 * i;        // j = r*32 + k4
        int r = j >> 5;
        int k4 = j & 31;
        int row = rowBase + r;
        float4 v = make_float4(0.f, 0.f, 0.f, 0.f);
        if (row < nrows) {
            v = ((const float4*)(X + (size_t)row * F_DIM))[k4];
            if (pout != nullptr && row >= U_USERS)
                ((float4*)(pout + (size_t)row * F_DIM))[k4] = v;   // fused passthrough
        }
        H4 p;
#pragma unroll
        for (int q = 0; q < 4; ++q) p.h[q] = (_Float16)((const float*)&v)[q];
        *(uint2*)&Xs[r * XPAD + k4 * 4] = p.u2;
    }
    __syncthreads();

    int w = tid >> 6;
    int lane = tid & 63;
    int m = lane & 15;
    int quad = lane >> 4;
    int R = w * 16;                   // block-local row base for this wave

    f32x4 acc[8];
#pragma unroll
    for (int i = 0; i < 8; ++i) acc[i] = (f32x4){0.f, 0.f, 0.f, 0.f};

#pragma unroll
    for (int kc = 0; kc < 4; ++kc) {
        f16x8 a = *(const f16x8*)&Xs[(R + m) * XPAD + kc * 32 + quad * 8];
#pragma unroll
        for (int ct = 0; ct < 8; ++ct) {
            f16x8 b = *(const f16x8*)&Wt[(ct * 16 + m) * XPAD + kc * 32 + quad * 8];
            acc[ct] = __builtin_amdgcn_mfma_f32_16x16x32_f16(a, b, acc[ct], 0, 0, 0);
        }
    }

#pragma unroll
    for (int ct = 0; ct < 8; ++ct) {
#pragma unroll
        for (int reg = 0; reg < 4; ++reg) {
            int row = rowBase + R + quad * 4 + reg;
            if (row < nrows)
                outh[(size_t)row * F_DIM + ct * 16 + m] = (_Float16)acc[ct][reg];
        }
    }
}

__global__ __launch_bounds__(256) void gemm_f16_kernel(const float* __restrict__ X,
                                                       const float* __restrict__ W,
                                                       _Float16* __restrict__ outh,
                                                       float* __restrict__ pout, int nrows) {
    gemm_mfma_body(X, W, outh, pout, nrows, blockIdx.x * 64);
}

__global__ __launch_bounds__(256) void gemm_f16_dyn_kernel(const float* __restrict__ X,
                                                           const float* __restrict__ W,
                                                           _Float16* __restrict__ outh,
                                                           const int* __restrict__ nrows_p) {
    int nrows = *nrows_p;
    int rowBase = blockIdx.x * 64;
    if (rowBase >= nrows) return;
    gemm_mfma_body(X, W, outh, nullptr, nrows, rowBase);
}

// ---- layer-1 gather over compact frontier rows (fp16 rows, fp32 accum) ----
__global__ __launch_bounds__(256) void gather_l1_kernel(const _Float16* __restrict__ xwh,
                                                        const float* __restrict__ inv,
                                                        const int* __restrict__ rp,
                                                        const int* __restrict__ col,
                                                        const int* __restrict__ flist,
                                                        const int* __restrict__ nf_p,
                                                        const float* __restrict__ b,
                                                        float* __restrict__ h1c) {
    int ci = blockIdx.x * 4 + (threadIdx.x >> 6);
    if (ci >= *nf_p) return;
    int lane = threadIdx.x & 63;
    int node = flist[ci];
    int start = (node == 0) ? 0 : rp[node - 1];
    int end = rp[node];

    float accx = 0.f, accy = 0.f;
    for (int base = start; base < end; base += 64) {
        int j = base + lane;
        int s_l = 0; float c_l = 0.f;
        if (j < end) { s_l = col[j]; c_l = inv[s_l]; }
        int cnt = min(64, end - base);
        int i = 0;
        for (; i + 4 <= cnt; i += 4) {
            int s0 = __shfl(s_l, i + 0); float f0 = __shfl(c_l, i + 0);
            int s1 = __shfl(s_l, i + 1); float f1 = __shfl(c_l, i + 1);
            int s2 = __shfl(s_l, i + 2); float f2 = __shfl(c_l, i + 2);
            int s3 = __shfl(s_l, i + 3); float f3 = __shfl(c_l, i + 3);
            f16x2 v0 = ((const f16x2*)(xwh + (size_t)s0 * F_DIM))[lane];
            f16x2 v1 = ((const f16x2*)(xwh + (size_t)s1 * F_DIM))[lane];
            f16x2 v2 = ((const f16x2*)(xwh + (size_t)s2 * F_DIM))[lane];
            f16x2 v3 = ((const f16x2*)(xwh + (size_t)s3 * F_DIM))[lane];
            accx += (float)v0[0] * f0 + (float)v1[0] * f1 + (float)v2[0] * f2 + (float)v3[0] * f3;
            accy += (float)v0[1] * f0 + (float)v1[1] * f1 + (float)v2[1] * f2 + (float)v3[1] * f3;
        }
        for (; i < cnt; ++i) {
            int s0 = __shfl(s_l, i); float f0 = __shfl(c_l, i);
            f16x2 v0 = ((const f16x2*)(xwh + (size_t)s0 * F_DIM))[lane];
            accx += (float)v0[0] * f0;
            accy += (float)v0[1] * f0;
        }
    }

    float ivd = inv[node];
    f16x2 self = ((const f16x2*)(xwh + (size_t)node * F_DIM))[lane];
    float vx = accx * ivd + (float)self[0] * ivd * ivd + b[lane * 2];
    float vy = accy * ivd + (float)self[1] * ivd * ivd + b[lane * 2 + 1];
    vx = vx > 0.f ? vx : expf(vx) - 1.f;
    vy = vy > 0.f ? vy : expf(vy) - 1.f;
    ((float2*)(h1c + (size_t)ci * F_DIM))[lane] = make_float2(vx, vy);
}

// ---- layer-2 gather over rows [0,U) (fp16 compact rows) ----
__global__ __launch_bounds__(256) void gather_l2_kernel(const _Float16* __restrict__ xwc,
                                                        const float* __restrict__ inv,
                                                        const int* __restrict__ rp,
                                                        const int* __restrict__ col,
                                                        const int* __restrict__ remap,
                                                        const float* __restrict__ b,
                                                        float* __restrict__ out) {
    int node = blockIdx.x * 4 + (threadIdx.x >> 6);
    if (node >= U_USERS) return;
    int lane = threadIdx.x & 63;
    int start = (node == 0) ? 0 : rp[node - 1];
    int end = rp[node];

    float accx = 0.f, accy = 0.f;
    for (int base = start; base < end; base += 64) {
        int j = base + lane;
        int r_l = 0; float c_l = 0.f;
        if (j < end) { int s = col[j]; c_l = inv[s]; r_l = remap[s]; }
        int cnt = min(64, end - base);
        int i = 0;
        for (; i + 4 <= cnt; i += 4) {
            int r0 = __shfl(r_l, i + 0); float f0 = __shfl(c_l, i + 0);
            int r1 = __shfl(r_l, i + 1); float f1 = __shfl(c_l, i + 1);
            int r2 = __shfl(r_l, i + 2); float f2 = __shfl(c_l, i + 2);
            int r3 = __shfl(r_l, i + 3); float f3 = __shfl(c_l, i + 3);
            f16x2 v0 = ((const f16x2*)(xwc + (size_t)r0 * F_DIM))[lane];
            f16x2 v1 = ((const f16x2*)(xwc + (size_t)r1 * F_DIM))[lane];
            f16x2 v2 = ((const f16x2*)(xwc + (size_t)r2 * F_DIM))[lane];
            f16x2 v3 = ((const f16x2*)(xwc + (size_t)r3 * F_DIM))[lane];
            accx += (float)v0[0] * f0 + (float)v1[0] * f1 + (float)v2[0] * f2 + (float)v3[0] * f3;
            accy += (float)v0[1] * f0 + (float)v1[1] * f1 + (float)v2[1] * f2 + (float)v3[1] * f3;
        }
        for (; i < cnt; ++i) {
            int rr = __shfl(r_l, i); float f0 = __shfl(c_l, i);
            f16x2 v0 = ((const f16x2*)(xwc + (size_t)rr * F_DIM))[lane];
            accx += (float)v0[0] * f0;
            accy += (float)v0[1] * f0;
        }
    }

    float ivd = inv[node];
    f16x2 self = ((const f16x2*)(xwc + (size_t)node * F_DIM))[lane];  // remap[node]==node for node<U
    float vx = accx * ivd + (float)self[0] * ivd * ivd + b[lane * 2];
    float vy = accy * ivd + (float)self[1] * ivd * ivd + b[lane * 2 + 1];
    vx = vx > 0.f ? vx : expf(vx) - 1.f;
    vy = vy > 0.f ? vy : expf(vy) - 1.f;
    ((float2*)(out + (size_t)node * F_DIM))[lane] = make_float2(vx, vy);
}

extern "C" void kernel_launch(void* const* d_in, const int* in_sizes, int n_in,
                              void* d_out, int out_size, void* d_ws, size_t ws_size,
                              hipStream_t stream) {
    const float* x  = (const float*)d_in[0];
    const int*   ei = (const int*)d_in[1];   // [2, E] int32
    const float* W1 = (const float*)d_in[2];
    const float* b1 = (const float*)d_in[3];
    const float* W2 = (const float*)d_in[4];
    const float* b2 = (const float*)d_in[5];
    float* out = (float*)d_out;

    int n = in_sizes[0] / F_DIM;   // 100000
    int E = in_sizes[1] / 2;       // 3200000
    const int* srcI = ei;
    const int* dstI = ei + E;

    // workspace layout (~110 MB)
    _Float16* xwh = (_Float16*)d_ws;                 // n*128 halfs (xw1 / xwc, 25.6MB)
    float* h1c   = (float*)(xwh + (size_t)n * F_DIM);// NFCAP*128 f (24.6MB)
    float* inv   = h1c + (size_t)NFCAP * F_DIM;      // n f
    int* fr      = (int*)(inv + n);                  // n
    int* degF    = fr + n;                           // n
    int* remap   = degF + n;                         // n
    int* rp      = remap + n;                        // n
    int* flist   = rp + n;                           // NFCAP
    int* pA      = flist + NFCAP;                    // 1024
    int* pB      = pA + 1024;                        // 1024
    int* nf_dev  = pB + 1024;                        // 1 (+pad)
    int* col     = nf_dev + 16;                      // E
    unsigned int* partialH = (unsigned int*)(col + E);  // NCHUNK*PSLICE*SW
    unsigned char* frB = (unsigned char*)(partialH + (size_t)NCHUNK * PSLICE * SW); // n bytes

    int nb = (n + SCAN_CHUNK - 1) / SCAN_CHUNK;      // 98

    hipMemsetAsync(fr, 0, (size_t)n * sizeof(int), stream);

    hist_kernel<<<NCHUNK * PSLICE, 1024, 0, stream>>>(srcI, dstI, partialH, fr, E, n);
    reduce_prep_kernel<<<(NCHUNK * SW + 255) / 256, 256, 0, stream>>>(partialH, inv, fr, degF, frB, n);

    scan_reduce2_kernel<<<nb, 256, 0, stream>>>(degF, fr, pA, pB, n);
    scan_partials2_kernel<<<1, 128, 0, stream>>>(pA, pB, nb);
    scan_final2_kernel<<<nb, 256, 0, stream>>>(degF, pA, rp, fr, pB, remap, flist, nf_dev, n);

    fill_csr_kernel<<<(E / 4 + 255) / 256, 256, 0, stream>>>(srcI, dstI, frB, rp, col, E, n);

    // layer 1: full MFMA GEMM (fp16 out) + fused passthrough, frontier-only gather
    gemm_f16_kernel<<<(n + 63) / 64, 256, 0, stream>>>(x, W1, xwh, out, n);
    gather_l1_kernel<<<(NFCAP + 3) / 4, 256, 0, stream>>>(xwh, inv, rp, col, flist, nf_dev, b1, h1c);

    // layer 2: compact MFMA GEMM (nf rows), gather over U rows
    gemm_f16_dyn_kernel<<<(NFCAP + 63) / 64, 256, 0, stream>>>(h1c, W2, xwh, nf_dev);
    gather_l2_kernel<<<(U_USERS + 3) / 4, 256, 0, stream>>>(xwh, inv, rp, col, remap, b2, out);
}

// Round 3
// 308.834 us; speedup vs baseline: 1.0812x; 1.0186x over previous
//
#include <hip/hip_runtime.h>

// GCNLinkPredictor: 2-layer GCN, N=100000, E=3.2M, F=128, U=1000.
// R10: fill_csr divergent-transaction attack.
//   R8/R9 lesson: MLP restructuring (split-phase atomics) barely moved
//   fill_csr (56/68/60us) because the kernel is bounded by divergent
//   vector-mem transaction ISSUE (3.2M flag gathers + 1.07M atomics +
//   1.07M stores), not atomic latency. This round deletes the 3.2M
//   global flag gathers: frontier flags become a 12.5KB bitmask staged
//   in LDS per block; flag check = LDS bit test (random LDS across 64
//   lanes ~ 2 lanes/bank = free, m136).
//   Also: scan_partials2's two serial 98-iter single-lane loops ->
//   wave shuffle-scans (2 waves, one per array).
// Carried: split-phase atomics (R9), hist int4 (R8), gemm passthrough
// fusion (R8), gather_l2 4-edge unroll (R8).

#define F_DIM 128
#define U_USERS 1000
#define SCAN_CHUNK 1024
#define NFCAP 48000     // frontier cap (expected ~33K)
#define NCHUNK 3        // node-space chunks for histogram
#define SBIN 40960      // nodes per chunk (3*40960 >= 100000)
#define SW (SBIN / 2)   // packed words per chunk (2 x u16 per word)
#define PSLICE 85       // edge slices per chunk -> 255 blocks
#define XPAD 136        // fp16 LDS row stride (128 + 8)
#define BMW 3136        // frontier bitmask words (ceil(100000/32)=3125, padded)

using f16x8 = __attribute__((ext_vector_type(8))) _Float16;
using f16x2 = __attribute__((ext_vector_type(2))) _Float16;
using f32x4 = __attribute__((ext_vector_type(4))) float;

union H4 { uint2 u2; _Float16 h[4]; };

// ---- histogram: LDS packed counters, no global atomics ----
__global__ __launch_bounds__(1024) void hist_kernel(const int* __restrict__ src,
                                                    const int* __restrict__ dst,
                                                    unsigned int* __restrict__ partial,
                                                    int* __restrict__ fr, int E, int n) {
    __shared__ unsigned int h[SW];   // 80 KB
    int tid = threadIdx.x;
    int c = blockIdx.x % NCHUNK;
    int p = blockIdx.x / NCHUNK;
    for (int i = tid; i < SW; i += 1024) h[i] = 0u;
    __syncthreads();

    int lo = c * SBIN;
    int hi = lo + SBIN;
    int len = (E + PSLICE - 1) / PSLICE;
    int base = p * len;
    int end = min(E, base + len);
    // vectorized: 4 edges per thread per iteration
    int e = base + tid * 4;
    for (; e + 3 < end; e += 4096) {
        int4 dv = *(const int4*)(dst + e);
#pragma unroll
        for (int i = 0; i < 4; ++i) {
            int d = ((const int*)&dv)[i];
            if ((unsigned)d < (unsigned)n) {
                if (d >= lo && d < hi) {
                    int local = d - lo;
                    atomicAdd(&h[local >> 1], 1u << ((local & 1) << 4));
                }
                if (c == 0 && d < U_USERS) {
                    int s = src[e + i];
                    if ((unsigned)s < (unsigned)n) fr[s] = 1;
                }
            }
        }
    }
    for (; e < end; ++e) {   // tail (rare)
        int d = dst[e];
        if ((unsigned)d < (unsigned)n) {
            if (d >= lo && d < hi) {
                int local = d - lo;
                atomicAdd(&h[local >> 1], 1u << ((local & 1) << 4));
            }
            if (c == 0 && d < U_USERS) {
                int s = src[e];
                if ((unsigned)s < (unsigned)n) fr[s] = 1;
            }
        }
    }
    __syncthreads();
    unsigned int* outp = partial + ((size_t)(c * PSLICE + p)) * SW;
    for (int i = tid; i < SW; i += 1024) outp[i] = h[i];
}

// ---- reduce partials -> deg; fused prep: inv, degF, fr[i<U]=1, bitmask ----
__global__ void reduce_prep_kernel(const unsigned int* __restrict__ partial,
                                   float* __restrict__ inv, int* __restrict__ fr,
                                   int* __restrict__ degF,
                                   unsigned int* __restrict__ bitsG, int n) {
    int t = blockIdx.x * blockDim.x + threadIdx.x;
    if (t >= NCHUNK * SW) return;
    int c = t / SW, w = t % SW;
    unsigned int a0 = 0, a1 = 0;
    const unsigned int* basep = partial + (size_t)c * PSLICE * SW + w;
#pragma unroll 5
    for (int p = 0; p < PSLICE; ++p) {
        unsigned int v = basep[(size_t)p * SW];
        a0 += v & 0xFFFFu;
        a1 += v >> 16;
    }
    int i0 = c * SBIN + 2 * w;   // even
    unsigned int pair = 0u;
#pragma unroll
    for (int k = 0; k < 2; ++k) {
        int i = i0 + k;
        unsigned int dg = k ? a1 : a0;
        if (i < n) {
            inv[i] = rsqrtf((float)dg + 1.0f);
            bool isfr = (i < U_USERS) || (fr[i] != 0);
            if (i < U_USERS) fr[i] = 1;
            degF[i] = isfr ? (int)dg : 0;
            if (isfr) pair |= (1u << k);
        }
    }
    if (pair) atomicOr(&bitsG[i0 >> 5], pair << (i0 & 31));
}

// ---- dual exclusive scan (degF -> rp, fr -> remap), 3 kernels ----
__global__ void scan_reduce2_kernel(const int* __restrict__ dA, const int* __restrict__ dB,
                                    int* __restrict__ pA, int* __restrict__ pB, int n) {
    __shared__ int sdata[256];
    int b = blockIdx.x, t = threadIdx.x;
    int base = b * SCAN_CHUNK;
    int sumA = 0, sumB = 0;
#pragma unroll
    for (int i = 0; i < 4; ++i) {
        int idx = base + t + 256 * i;
        if (idx < n) { sumA += dA[idx]; sumB += dB[idx]; }
    }
    sdata[t] = sumA; __syncthreads();
    for (int s = 128; s > 0; s >>= 1) { if (t < s) sdata[t] += sdata[t + s]; __syncthreads(); }
    if (t == 0) pA[b] = sdata[0];
    __syncthreads();
    sdata[t] = sumB; __syncthreads();
    for (int s = 128; s > 0; s >>= 1) { if (t < s) sdata[t] += sdata[t + s]; __syncthreads(); }
    if (t == 0) pB[b] = sdata[0];
}

// two waves: wave0 scans pA, wave1 scans pB; nb <= 128 (nb=98)
__global__ void scan_partials2_kernel(int* __restrict__ pA, int* __restrict__ pB, int nb) {
    int wv = threadIdx.x >> 6, lane = threadIdx.x & 63;
    int* p = wv ? pB : pA;
    int i0 = lane * 2, i1 = lane * 2 + 1;
    int v0 = (i0 < nb) ? p[i0] : 0;
    int v1 = (i1 < nb) ? p[i1] : 0;
    int sum = v0 + v1;
    int incl = sum;
    for (int ofs = 1; ofs < 64; ofs <<= 1) {
        int t = __shfl_up(incl, ofs);
        if (lane >= ofs) incl += t;
    }
    int run = incl - sum;   // exclusive base for this lane's segment
    if (i0 < nb) p[i0] = run;
    if (i1 < nb) p[i1] = run + v0;
}

__global__ void scan_final2_kernel(const int* __restrict__ dA, const int* __restrict__ pA,
                                   int* __restrict__ rp,
                                   const int* __restrict__ dB, const int* __restrict__ pB,
                                   int* __restrict__ remap,
                                   int* __restrict__ flist, int* __restrict__ nf_dev, int n) {
    __shared__ int sthread[256];
    int b = blockIdx.x, t = threadIdx.x;
    int base = b * SCAN_CHUNK;
    {
        int v[4]; int sum = 0;
#pragma unroll
        for (int i = 0; i < 4; ++i) { int idx = base + 4 * t + i; v[i] = (idx < n) ? dA[idx] : 0; sum += v[i]; }
        sthread[t] = sum; __syncthreads();
        for (int ofs = 1; ofs < 256; ofs <<= 1) {
            int val = (t >= ofs) ? sthread[t - ofs] : 0;
            __syncthreads(); sthread[t] += val; __syncthreads();
        }
        int run = sthread[t] - sum + pA[b];
#pragma unroll
        for (int i = 0; i < 4; ++i) { int idx = base + 4 * t + i; if (idx < n) rp[idx] = run; run += v[i]; }
        __syncthreads();
    }
    {
        int v[4]; int sum = 0;
#pragma unroll
        for (int i = 0; i < 4; ++i) { int idx = base + 4 * t + i; v[i] = (idx < n) ? dB[idx] : 0; sum += v[i]; }
        sthread[t] = sum; __syncthreads();
        for (int ofs = 1; ofs < 256; ofs <<= 1) {
            int val = (t >= ofs) ? sthread[t - ofs] : 0;
            __syncthreads(); sthread[t] += val; __syncthreads();
        }
        int run = sthread[t] - sum + pB[b];
#pragma unroll
        for (int i = 0; i < 4; ++i) {
            int idx = base + 4 * t + i;
            if (idx < n) {
                remap[idx] = run;
                if (v[i] && run < NFCAP) flist[run] = idx;
                if (idx == n - 1) *nf_dev = min(run + v[i], NFCAP);
            }
            run += v[i];
        }
    }
}

// ---- CSR fill: LDS bitmask flags + 4 edges/thread split-phase ----
__global__ __launch_bounds__(256) void fill_csr_kernel(const int* __restrict__ src,
                                                       const int* __restrict__ dst,
                                                       const unsigned int* __restrict__ bitsG,
                                                       int* __restrict__ rp, int* __restrict__ col,
                                                       int E, int n) {
    __shared__ unsigned int bm[BMW];   // 12.5 KB
    int tid = threadIdx.x;
    int nw = (n + 31) >> 5;
    for (int i = tid; i < nw; i += 256) bm[i] = bitsG[i];
    __syncthreads();

    int t = blockIdx.x * 256 + tid;
    int e0 = t * 4;
    if (e0 + 3 < E) {
        int4 dv = *(const int4*)(dst + e0);
        int4 sv = *(const int4*)(src + e0);
        const int* dp = (const int*)&dv;
        const int* sp = (const int*)&sv;
        // phase 1: 4 independent LDS bit tests (no global txns)
        bool f[4];
#pragma unroll
        for (int i = 0; i < 4; ++i) {
            int d = dp[i];
            f[i] = ((unsigned)d < (unsigned)n) && ((unsigned)sp[i] < (unsigned)n)
                   && ((bm[d >> 5] >> (d & 31)) & 1u);
        }
        // phase 2: issue all 4 atomics; results not consumed -> in flight together
        int pos[4];
#pragma unroll
        for (int i = 0; i < 4; ++i) {
            pos[i] = -1;
            if (f[i]) pos[i] = atomicAdd(&rp[dp[i]], 1);
        }
        // phase 3: one wait, 4 independent scattered stores
#pragma unroll
        for (int i = 0; i < 4; ++i) {
            if (f[i] && (unsigned)pos[i] < (unsigned)E) col[pos[i]] = sp[i];
        }
    } else {
        for (int e = e0; e < E; ++e) {
            int d = dst[e], s = src[e];
            if ((unsigned)d < (unsigned)n && (unsigned)s < (unsigned)n &&
                ((bm[d >> 5] >> (d & 31)) & 1u)) {
                int pos = atomicAdd(&rp[d], 1);
                if ((unsigned)pos < (unsigned)E) col[pos] = s;
            }
        }
    }
}

// ---- MFMA fp16 GEMM: outh[n,128] = f16(X[n,128] @ W[128,128]) ----
// 256 threads = 4 waves, 64 rows/block. LDS: Xs fp16 [64][136] (17KB) +
// Wt fp16 (W transposed, [n][k]) [128][136] (34KB) -> 3 blocks/CU.
// Wave w: rows [16w,16w+16), all 128 cols (8 col-tiles), K=128 in 4 chunks.
// pout != nullptr: also store raw x rows >= U to out (fused passthrough).
__device__ __forceinline__ void gemm_mfma_body(const float* __restrict__ X,
                                               const float* __restrict__ W,
                                               _Float16* __restrict__ outh,
                                               float* __restrict__ pout,
                                               int nrows, int rowBase) {
    __shared__ _Float16 Wt[128 * XPAD];   // [n][k]
    __shared__ _Float16 Xs[64 * XPAD];    // [r][k]

    int tid = threadIdx.x;

    // stage W transposed: 4096 float4s / 256 threads = 16 each
    const float4* W4 = (const float4*)W;
#pragma unroll
    for (int i = 0; i < 16; ++i) {
        int j = tid + 256 * i;        // j = k*32 + n4
        int k = j >> 5;
        int n4 = j & 31;
        float4 v = W4[j];
#pragma unroll
        for (int q = 0; q < 4; ++q)
            Wt[(n4 * 4 + q) * XPAD + k] = (_Float16)((const float*)&v)[q];
    }

    // stage X tile fp16 row-major: 2048 float4s / 256 = 8 each
#pragma unroll
    for (int i = 0; i < 8; ++i) {
        int j = tid + 256 * i;        // j = r*32 + k4
        int r = j >> 5;
        int k4 = j & 31;
        int row = rowBase + r;
        float4 v = make_float4(0.f, 0.f, 0.f, 0.f);
        if (row < nrows) {
            v = ((const float4*)(X + (size_t)row * F_DIM))[k4];
            if (pout != nullptr && row >= U_USERS)
                ((float4*)(pout + (size_t)row * F_DIM))[k4] = v;   // fused passthrough
        }
        H4 p;
#pragma unroll
        for (int q = 0; q < 4; ++q) p.h[q] = (_Float16)((const float*)&v)[q];
        *(uint2*)&Xs[r * XPAD + k4 * 4] = p.u2;
    }
    __syncthreads();

    int w = tid >> 6;
    int lane = tid & 63;
    int m = lane & 15;
    int quad = lane >> 4;
    int R = w * 16;                   // block-local row base for this wave

    f32x4 acc[8];
#pragma unroll
    for (int i = 0; i < 8; ++i) acc[i] = (f32x4){0.f, 0.f, 0.f, 0.f};

#pragma unroll
    for (int kc = 0; kc < 4; ++kc) {
        f16x8 a = *(const f16x8*)&Xs[(R + m) * XPAD + kc * 32 + quad * 8];
#pragma unroll
        for (int ct = 0; ct < 8; ++ct) {
            f16x8 b = *(const f16x8*)&Wt[(ct * 16 + m) * XPAD + kc * 32 + quad * 8];
            acc[ct] = __builtin_amdgcn_mfma_f32_16x16x32_f16(a, b, acc[ct], 0, 0, 0);
        }
    }

#pragma unroll
    for (int ct = 0; ct < 8; ++ct) {
#pragma unroll
        for (int reg = 0; reg < 4; ++reg) {
            int row = rowBase + R + quad * 4 + reg;
            if (row < nrows)
                outh[(size_t)row * F_DIM + ct * 16 + m] = (_Float16)acc[ct][reg];
        }
    }
}

__global__ __launch_bounds__(256) void gemm_f16_kernel(const float* __restrict__ X,
                                                       const float* __restrict__ W,
                                                       _Float16* __restrict__ outh,
                                                       float* __restrict__ pout, int nrows) {
    gemm_mfma_body(X, W, outh, pout, nrows, blockIdx.x * 64);
}

__global__ __launch_bounds__(256) void gemm_f16_dyn_kernel(const float* __restrict__ X,
                                                           const float* __restrict__ W,
                                                           _Float16* __restrict__ outh,
                                                           const int* __restrict__ nrows_p) {
    int nrows = *nrows_p;
    int rowBase = blockIdx.x * 64;
    if (rowBase >= nrows) return;
    gemm_mfma_body(X, W, outh, nullptr, nrows, rowBase);
}

// ---- layer-1 gather over compact frontier rows (fp16 rows, fp32 accum) ----
__global__ __launch_bounds__(256) void gather_l1_kernel(const _Float16* __restrict__ xwh,
                                                        const float* __restrict__ inv,
                                                        const int* __restrict__ rp,
                                                        const int* __restrict__ col,
                                                        const int* __restrict__ flist,
                                                        const int* __restrict__ nf_p,
                                                        const float* __restrict__ b,
                                                        float* __restrict__ h1c) {
    int ci = blockIdx.x * 4 + (threadIdx.x >> 6);
    if (ci >= *nf_p) return;
    int lane = threadIdx.x & 63;
    int node = flist[ci];
    int start = (node == 0) ? 0 : rp[node - 1];
    int end = rp[node];

    float accx = 0.f, accy = 0.f;
    for (int base = start; base < end; base += 64) {
        int j = base + lane;
        int s_l = 0; float c_l = 0.f;
        if (j < end) { s_l = col[j]; c_l = inv[s_l]; }
        int cnt = min(64, end - base);
        int i = 0;
        for (; i + 4 <= cnt; i += 4) {
            int s0 = __shfl(s_l, i + 0); float f0 = __shfl(c_l, i + 0);
            int s1 = __shfl(s_l, i + 1); float f1 = __shfl(c_l, i + 1);
            int s2 = __shfl(s_l, i + 2); float f2 = __shfl(c_l, i + 2);
            int s3 = __shfl(s_l, i + 3); float f3 = __shfl(c_l, i + 3);
            f16x2 v0 = ((const f16x2*)(xwh + (size_t)s0 * F_DIM))[lane];
            f16x2 v1 = ((const f16x2*)(xwh + (size_t)s1 * F_DIM))[lane];
            f16x2 v2 = ((const f16x2*)(xwh + (size_t)s2 * F_DIM))[lane];
            f16x2 v3 = ((const f16x2*)(xwh + (size_t)s3 * F_DIM))[lane];
            accx += (float)v0[0] * f0 + (float)v1[0] * f1 + (float)v2[0] * f2 + (float)v3[0] * f3;
            accy += (float)v0[1] * f0 + (float)v1[1] * f1 + (float)v2[1] * f2 + (float)v3[1] * f3;
        }
        for (; i < cnt; ++i) {
            int s0 = __shfl(s_l, i); float f0 = __shfl(c_l, i);
            f16x2 v0 = ((const f16x2*)(xwh + (size_t)s0 * F_DIM))[lane];
            accx += (float)v0[0] * f0;
            accy += (float)v0[1] * f0;
        }
    }

    float ivd = inv[node];
    f16x2 self = ((const f16x2*)(xwh + (size_t)node * F_DIM))[lane];
    float vx = accx * ivd + (float)self[0] * ivd * ivd + b[lane * 2];
    float vy = accy * ivd + (float)self[1] * ivd * ivd + b[lane * 2 + 1];
    vx = vx > 0.f ? vx : expf(vx) - 1.f;
    vy = vy > 0.f ? vy : expf(vy) - 1.f;
    ((float2*)(h1c + (size_t)ci * F_DIM))[lane] = make_float2(vx, vy);
}

// ---- layer-2 gather over rows [0,U) (fp16 compact rows) ----
__global__ __launch_bounds__(256) void gather_l2_kernel(const _Float16* __restrict__ xwc,
                                                        const float* __restrict__ inv,
                                                        const int* __restrict__ rp,
                                                        const int* __restrict__ col,
                                                        const int* __restrict__ remap,
                                                        const float* __restrict__ b,
                                                        float* __restrict__ out) {
    int node = blockIdx.x * 4 + (threadIdx.x >> 6);
    if (node >= U_USERS) return;
    int lane = threadIdx.x & 63;
    int start = (node == 0) ? 0 : rp[node - 1];
    int end = rp[node];

    float accx = 0.f, accy = 0.f;
    for (int base = start; base < end; base += 64) {
        int j = base + lane;
        int r_l = 0; float c_l = 0.f;
        if (j < end) { int s = col[j]; c_l = inv[s]; r_l = remap[s]; }
        int cnt = min(64, end - base);
        int i = 0;
        for (; i + 4 <= cnt; i += 4) {
            int r0 = __shfl(r_l, i + 0); float f0 = __shfl(c_l, i + 0);
            int r1 = __shfl(r_l, i + 1); float f1 = __shfl(c_l, i + 1);
            int r2 = __shfl(r_l, i + 2); float f2 = __shfl(c_l, i + 2);
            int r3 = __shfl(r_l, i + 3); float f3 = __shfl(c_l, i + 3);
            f16x2 v0 = ((const f16x2*)(xwc + (size_t)r0 * F_DIM))[lane];
            f16x2 v1 = ((const f16x2*)(xwc + (size_t)r1 * F_DIM))[lane];
            f16x2 v2 = ((const f16x2*)(xwc + (size_t)r2 * F_DIM))[lane];
            f16x2 v3 = ((const f16x2*)(xwc + (size_t)r3 * F_DIM))[lane];
            accx += (float)v0[0] * f0 + (float)v1[0] * f1 + (float)v2[0] * f2 + (float)v3[0] * f3;
            accy += (float)v0[1] * f0 + (float)v1[1] * f1 + (float)v2[1] * f2 + (float)v3[1] * f3;
        }
        for (; i < cnt; ++i) {
            int rr = __shfl(r_l, i); float f0 = __shfl(c_l, i);
            f16x2 v0 = ((const f16x2*)(xwc + (size_t)rr * F_DIM))[lane];
            accx += (float)v0[0] * f0;
            accy += (float)v0[1] * f0;
        }
    }

    float ivd = inv[node];
    f16x2 self = ((const f16x2*)(xwc + (size_t)node * F_DIM))[lane];  // remap[node]==node for node<U
    float vx = accx * ivd + (float)self[0] * ivd * ivd + b[lane * 2];
    float vy = accy * ivd + (float)self[1] * ivd * ivd + b[lane * 2 + 1];
    vx = vx > 0.f ? vx : expf(vx) - 1.f;
    vy = vy > 0.f ? vy : expf(vy) - 1.f;
    ((float2*)(out + (size_t)node * F_DIM))[lane] = make_float2(vx, vy);
}

extern "C" void kernel_launch(void* const* d_in, const int* in_sizes, int n_in,
                              void* d_out, int out_size, void* d_ws, size_t ws_size,
                              hipStream_t stream) {
    const float* x  = (const float*)d_in[0];
    const int*   ei = (const int*)d_in[1];   // [2, E] int32
    const float* W1 = (const float*)d_in[2];
    const float* b1 = (const float*)d_in[3];
    const float* W2 = (const float*)d_in[4];
    const float* b2 = (const float*)d_in[5];
    float* out = (float*)d_out;

    int n = in_sizes[0] / F_DIM;   // 100000
    int E = in_sizes[1] / 2;       // 3200000
    const int* srcI = ei;
    const int* dstI = ei + E;

    // workspace layout (~110 MB)
    _Float16* xwh = (_Float16*)d_ws;                 // n*128 halfs (xw1 / xwc, 25.6MB)
    float* h1c   = (float*)(xwh + (size_t)n * F_DIM);// NFCAP*128 f (24.6MB)
    float* inv   = h1c + (size_t)NFCAP * F_DIM;      // n f
    int* fr      = (int*)(inv + n);                  // n
    int* degF    = fr + n;                           // n
    int* remap   = degF + n;                         // n
    int* rp      = remap + n;                        // n
    int* flist   = rp + n;                           // NFCAP
    int* pA      = flist + NFCAP;                    // 1024
    int* pB      = pA + 1024;                        // 1024
    int* nf_dev  = pB + 1024;                        // 1 (+pad)
    int* col     = nf_dev + 16;                      // E
    unsigned int* partialH = (unsigned int*)(col + E);  // NCHUNK*PSLICE*SW
    unsigned int* bitsG = partialH + (size_t)NCHUNK * PSLICE * SW;  // BMW words

    int nb = (n + SCAN_CHUNK - 1) / SCAN_CHUNK;      // 98

    hipMemsetAsync(fr, 0, (size_t)n * sizeof(int), stream);
    hipMemsetAsync(bitsG, 0, (size_t)BMW * sizeof(unsigned int), stream);

    hist_kernel<<<NCHUNK * PSLICE, 1024, 0, stream>>>(srcI, dstI, partialH, fr, E, n);
    reduce_prep_kernel<<<(NCHUNK * SW + 255) / 256, 256, 0, stream>>>(partialH, inv, fr, degF, bitsG, n);

    scan_reduce2_kernel<<<nb, 256, 0, stream>>>(degF, fr, pA, pB, n);
    scan_partials2_kernel<<<1, 128, 0, stream>>>(pA, pB, nb);
    scan_final2_kernel<<<nb, 256, 0, stream>>>(degF, pA, rp, fr, pB, remap, flist, nf_dev, n);

    fill_csr_kernel<<<(E / 4 + 255) / 256, 256, 0, stream>>>(srcI, dstI, bitsG, rp, col, E, n);

    // layer 1: full MFMA GEMM (fp16 out) + fused passthrough, frontier-only gather
    gemm_f16_kernel<<<(n + 63) / 64, 256, 0, stream>>>(x, W1, xwh, out, n);
    gather_l1_kernel<<<(NFCAP + 3) / 4, 256, 0, stream>>>(xwh, inv, rp, col, flist, nf_dev, b1, h1c);

    // layer 2: compact MFMA GEMM (nf rows), gather over U rows
    gemm_f16_dyn_kernel<<<(NFCAP + 63) / 64, 256, 0, stream>>>(h1c, W2, xwh, nf_dev);
    gather_l2_kernel<<<(U_USERS + 3) / 4, 256, 0, stream>>>(xwh, inv, rp, col, remap, b2, out);
}

// Round 4
// 299.144 us; speedup vs baseline: 1.1162x; 1.0324x over previous
//
#include <hip/hip_runtime.h>

// GCNLinkPredictor: 2-layer GCN, N=100000, E=3.2M, F=128, U=1000.
// R11: overlap round — fuse gemm1 + fill_csr into ONE dispatch.
//   R8-R10 lesson: fill_csr is pinned at 56-60us across 4 structural
//   variants (1-edge, 4-edge, split-phase, LDS bitmask) with constant
//   FETCH 13MB / WRITE 58MB => ~1.0 TB/s line-granular scatter ==
//   intrinsic cost of 1.07M random 4B stores + atomics. All pipes idle
//   (VALU 4.5%, MFMA 0, HBM 15%). So: hide independent work under it.
//   gemm1 (x@W1, ~35us, MFMA+stream, no CSR deps) becomes block range
//   [0,1563) of the same dispatch; fill_csr becomes [1563,1563+3125).
//   Shared-mem union (52.2KB) keeps 3 blocks/CU for the gemm path.
// Carried: LDS bitmask flags (R10), split-phase atomics (R9), hist int4
// (R8), passthrough fused into gemm staging (R8), wave shuffle-scan
// partials (R10), gather 4-edge unrolls (R8).

#define F_DIM 128
#define U_USERS 1000
#define SCAN_CHUNK 1024
#define NFCAP 48000     // frontier cap (expected ~33K)
#define NCHUNK 3        // node-space chunks for histogram
#define SBIN 40960      // nodes per chunk (3*40960 >= 100000)
#define SW (SBIN / 2)   // packed words per chunk (2 x u16 per word)
#define PSLICE 85       // edge slices per chunk -> 255 blocks
#define XPAD 136        // fp16 LDS row stride (128 + 8)
#define BMW 3136        // frontier bitmask words (ceil(100000/32)=3125, padded)
#define SMEM_BYTES (128 * XPAD * 2 + 64 * XPAD * 2)   // 52224: Wt + Xs (>= bitmask 12.5KB)

using f16x8 = __attribute__((ext_vector_type(8))) _Float16;
using f16x2 = __attribute__((ext_vector_type(2))) _Float16;
using f32x4 = __attribute__((ext_vector_type(4))) float;

union H4 { uint2 u2; _Float16 h[4]; };

// ---- histogram: LDS packed counters, no global atomics ----
__global__ __launch_bounds__(1024) void hist_kernel(const int* __restrict__ src,
                                                    const int* __restrict__ dst,
                                                    unsigned int* __restrict__ partial,
                                                    int* __restrict__ fr, int E, int n) {
    __shared__ unsigned int h[SW];   // 80 KB
    int tid = threadIdx.x;
    int c = blockIdx.x % NCHUNK;
    int p = blockIdx.x / NCHUNK;
    for (int i = tid; i < SW; i += 1024) h[i] = 0u;
    __syncthreads();

    int lo = c * SBIN;
    int hi = lo + SBIN;
    int len = (E + PSLICE - 1) / PSLICE;
    int base = p * len;
    int end = min(E, base + len);
    // vectorized: 4 edges per thread per iteration
    int e = base + tid * 4;
    for (; e + 3 < end; e += 4096) {
        int4 dv = *(const int4*)(dst + e);
#pragma unroll
        for (int i = 0; i < 4; ++i) {
            int d = ((const int*)&dv)[i];
            if ((unsigned)d < (unsigned)n) {
                if (d >= lo && d < hi) {
                    int local = d - lo;
                    atomicAdd(&h[local >> 1], 1u << ((local & 1) << 4));
                }
                if (c == 0 && d < U_USERS) {
                    int s = src[e + i];
                    if ((unsigned)s < (unsigned)n) fr[s] = 1;
                }
            }
        }
    }
    for (; e < end; ++e) {   // tail (rare)
        int d = dst[e];
        if ((unsigned)d < (unsigned)n) {
            if (d >= lo && d < hi) {
                int local = d - lo;
                atomicAdd(&h[local >> 1], 1u << ((local & 1) << 4));
            }
            if (c == 0 && d < U_USERS) {
                int s = src[e];
                if ((unsigned)s < (unsigned)n) fr[s] = 1;
            }
        }
    }
    __syncthreads();
    unsigned int* outp = partial + ((size_t)(c * PSLICE + p)) * SW;
    for (int i = tid; i < SW; i += 1024) outp[i] = h[i];
}

// ---- reduce partials -> deg; fused prep: inv, degF, fr[i<U]=1, bitmask ----
__global__ void reduce_prep_kernel(const unsigned int* __restrict__ partial,
                                   float* __restrict__ inv, int* __restrict__ fr,
                                   int* __restrict__ degF,
                                   unsigned int* __restrict__ bitsG, int n) {
    int t = blockIdx.x * blockDim.x + threadIdx.x;
    if (t >= NCHUNK * SW) return;
    int c = t / SW, w = t % SW;
    unsigned int a0 = 0, a1 = 0;
    const unsigned int* basep = partial + (size_t)c * PSLICE * SW + w;
#pragma unroll 5
    for (int p = 0; p < PSLICE; ++p) {
        unsigned int v = basep[(size_t)p * SW];
        a0 += v & 0xFFFFu;
        a1 += v >> 16;
    }
    int i0 = c * SBIN + 2 * w;   // even
    unsigned int pair = 0u;
#pragma unroll
    for (int k = 0; k < 2; ++k) {
        int i = i0 + k;
        unsigned int dg = k ? a1 : a0;
        if (i < n) {
            inv[i] = rsqrtf((float)dg + 1.0f);
            bool isfr = (i < U_USERS) || (fr[i] != 0);
            if (i < U_USERS) fr[i] = 1;
            degF[i] = isfr ? (int)dg : 0;
            if (isfr) pair |= (1u << k);
        }
    }
    if (pair) atomicOr(&bitsG[i0 >> 5], pair << (i0 & 31));
}

// ---- dual exclusive scan (degF -> rp, fr -> remap), 3 kernels ----
__global__ void scan_reduce2_kernel(const int* __restrict__ dA, const int* __restrict__ dB,
                                    int* __restrict__ pA, int* __restrict__ pB, int n) {
    __shared__ int sdata[256];
    int b = blockIdx.x, t = threadIdx.x;
    int base = b * SCAN_CHUNK;
    int sumA = 0, sumB = 0;
#pragma unroll
    for (int i = 0; i < 4; ++i) {
        int idx = base + t + 256 * i;
        if (idx < n) { sumA += dA[idx]; sumB += dB[idx]; }
    }
    sdata[t] = sumA; __syncthreads();
    for (int s = 128; s > 0; s >>= 1) { if (t < s) sdata[t] += sdata[t + s]; __syncthreads(); }
    if (t == 0) pA[b] = sdata[0];
    __syncthreads();
    sdata[t] = sumB; __syncthreads();
    for (int s = 128; s > 0; s >>= 1) { if (t < s) sdata[t] += sdata[t + s]; __syncthreads(); }
    if (t == 0) pB[b] = sdata[0];
}

// two waves: wave0 scans pA, wave1 scans pB; nb <= 128 (nb=98)
__global__ void scan_partials2_kernel(int* __restrict__ pA, int* __restrict__ pB, int nb) {
    int wv = threadIdx.x >> 6, lane = threadIdx.x & 63;
    int* p = wv ? pB : pA;
    int i0 = lane * 2, i1 = lane * 2 + 1;
    int v0 = (i0 < nb) ? p[i0] : 0;
    int v1 = (i1 < nb) ? p[i1] : 0;
    int sum = v0 + v1;
    int incl = sum;
    for (int ofs = 1; ofs < 64; ofs <<= 1) {
        int t = __shfl_up(incl, ofs);
        if (lane >= ofs) incl += t;
    }
    int run = incl - sum;   // exclusive base for this lane's segment
    if (i0 < nb) p[i0] = run;
    if (i1 < nb) p[i1] = run + v0;
}

__global__ void scan_final2_kernel(const int* __restrict__ dA, const int* __restrict__ pA,
                                   int* __restrict__ rp,
                                   const int* __restrict__ dB, const int* __restrict__ pB,
                                   int* __restrict__ remap,
                                   int* __restrict__ flist, int* __restrict__ nf_dev, int n) {
    __shared__ int sthread[256];
    int b = blockIdx.x, t = threadIdx.x;
    int base = b * SCAN_CHUNK;
    {
        int v[4]; int sum = 0;
#pragma unroll
        for (int i = 0; i < 4; ++i) { int idx = base + 4 * t + i; v[i] = (idx < n) ? dA[idx] : 0; sum += v[i]; }
        sthread[t] = sum; __syncthreads();
        for (int ofs = 1; ofs < 256; ofs <<= 1) {
            int val = (t >= ofs) ? sthread[t - ofs] : 0;
            __syncthreads(); sthread[t] += val; __syncthreads();
        }
        int run = sthread[t] - sum + pA[b];
#pragma unroll
        for (int i = 0; i < 4; ++i) { int idx = base + 4 * t + i; if (idx < n) rp[idx] = run; run += v[i]; }
        __syncthreads();
    }
    {
        int v[4]; int sum = 0;
#pragma unroll
        for (int i = 0; i < 4; ++i) { int idx = base + 4 * t + i; v[i] = (idx < n) ? dB[idx] : 0; sum += v[i]; }
        sthread[t] = sum; __syncthreads();
        for (int ofs = 1; ofs < 256; ofs <<= 1) {
            int val = (t >= ofs) ? sthread[t - ofs] : 0;
            __syncthreads(); sthread[t] += val; __syncthreads();
        }
        int run = sthread[t] - sum + pB[b];
#pragma unroll
        for (int i = 0; i < 4; ++i) {
            int idx = base + 4 * t + i;
            if (idx < n) {
                remap[idx] = run;
                if (v[i] && run < NFCAP) flist[run] = idx;
                if (idx == n - 1) *nf_dev = min(run + v[i], NFCAP);
            }
            run += v[i];
        }
    }
}

// ---- fill_csr body: LDS bitmask flags + 4 edges/thread split-phase ----
__device__ __forceinline__ void fill_csr_body(const int* __restrict__ src,
                                              const int* __restrict__ dst,
                                              const unsigned int* __restrict__ bitsG,
                                              int* __restrict__ rp, int* __restrict__ col,
                                              int E, int n, int fblk,
                                              unsigned char* smem) {
    unsigned int* bm = (unsigned int*)smem;   // 12.5 KB of the union
    int tid = threadIdx.x;
    int nw = (n + 31) >> 5;
    for (int i = tid; i < nw; i += 256) bm[i] = bitsG[i];
    __syncthreads();

    int t = fblk * 256 + tid;
    int e0 = t * 4;
    if (e0 + 3 < E) {
        int4 dv = *(const int4*)(dst + e0);
        int4 sv = *(const int4*)(src + e0);
        const int* dp = (const int*)&dv;
        const int* sp = (const int*)&sv;
        // phase 1: 4 independent LDS bit tests (no global txns)
        bool f[4];
#pragma unroll
        for (int i = 0; i < 4; ++i) {
            int d = dp[i];
            f[i] = ((unsigned)d < (unsigned)n) && ((unsigned)sp[i] < (unsigned)n)
                   && ((bm[d >> 5] >> (d & 31)) & 1u);
        }
        // phase 2: issue all 4 atomics; results not consumed -> in flight together
        int pos[4];
#pragma unroll
        for (int i = 0; i < 4; ++i) {
            pos[i] = -1;
            if (f[i]) pos[i] = atomicAdd(&rp[dp[i]], 1);
        }
        // phase 3: one wait, 4 independent scattered stores
#pragma unroll
        for (int i = 0; i < 4; ++i) {
            if (f[i] && (unsigned)pos[i] < (unsigned)E) col[pos[i]] = sp[i];
        }
    } else {
        for (int e = e0; e < E; ++e) {
            int d = dst[e], s = src[e];
            if ((unsigned)d < (unsigned)n && (unsigned)s < (unsigned)n &&
                ((bm[d >> 5] >> (d & 31)) & 1u)) {
                int pos = atomicAdd(&rp[d], 1);
                if ((unsigned)pos < (unsigned)E) col[pos] = s;
            }
        }
    }
}

// ---- MFMA fp16 GEMM body: outh[n,128] = f16(X[n,128] @ W[128,128]) ----
// 256 threads = 4 waves, 64 rows/block. smem union: Wt fp16 [128][136]
// (34.8KB) + Xs fp16 [64][136] (17.4KB) = 52.2KB -> 3 blocks/CU.
// pout != nullptr: also store raw x rows >= U to out (fused passthrough).
__device__ __forceinline__ void gemm_mfma_body(const float* __restrict__ X,
                                               const float* __restrict__ W,
                                               _Float16* __restrict__ outh,
                                               float* __restrict__ pout,
                                               int nrows, int rowBase,
                                               unsigned char* smem) {
    _Float16* Wt = (_Float16*)smem;            // [n][k]
    _Float16* Xs = Wt + 128 * XPAD;            // [r][k]

    int tid = threadIdx.x;

    // stage W transposed: 4096 float4s / 256 threads = 16 each
    const float4* W4 = (const float4*)W;
#pragma unroll
    for (int i = 0; i < 16; ++i) {
        int j = tid + 256 * i;        // j = k*32 + n4
        int k = j >> 5;
        int n4 = j & 31;
        float4 v = W4[j];
#pragma unroll
        for (int q = 0; q < 4; ++q)
            Wt[(n4 * 4 + q) * XPAD + k] = (_Float16)((const float*)&v)[q];
    }

    // stage X tile fp16 row-major: 2048 float4s / 256 = 8 each
#pragma unroll
    for (int i = 0; i < 8; ++i) {
        int j = tid + 256 * i;        // j = r*32 + k4
        int r = j >> 5;
        int k4 = j & 31;
        int row = rowBase + r;
        float4 v = make_float4(0.f, 0.f, 0.f, 0.f);
        if (row < nrows) {
            v = ((const float4*)(X + (size_t)row * F_DIM))[k4];
            if (pout != nullptr && row >= U_USERS)
                ((float4*)(pout + (size_t)row * F_DIM))[k4] = v;   // fused passthrough
        }
        H4 p;
#pragma unroll
        for (int q = 0; q < 4; ++q) p.h[q] = (_Float16)((const float*)&v)[q];
        *(uint2*)&Xs[r * XPAD + k4 * 4] = p.u2;
    }
    __syncthreads();

    int w = tid >> 6;
    int lane = tid & 63;
    int m = lane & 15;
    int quad = lane >> 4;
    int R = w * 16;                   // block-local row base for this wave

    f32x4 acc[8];
#pragma unroll
    for (int i = 0; i < 8; ++i) acc[i] = (f32x4){0.f, 0.f, 0.f, 0.f};

#pragma unroll
    for (int kc = 0; kc < 4; ++kc) {
        f16x8 a = *(const f16x8*)&Xs[(R + m) * XPAD + kc * 32 + quad * 8];
#pragma unroll
        for (int ct = 0; ct < 8; ++ct) {
            f16x8 b = *(const f16x8*)&Wt[(ct * 16 + m) * XPAD + kc * 32 + quad * 8];
            acc[ct] = __builtin_amdgcn_mfma_f32_16x16x32_f16(a, b, acc[ct], 0, 0, 0);
        }
    }

#pragma unroll
    for (int ct = 0; ct < 8; ++ct) {
#pragma unroll
        for (int reg = 0; reg < 4; ++reg) {
            int row = rowBase + R + quad * 4 + reg;
            if (row < nrows)
                outh[(size_t)row * F_DIM + ct * 16 + m] = (_Float16)acc[ct][reg];
        }
    }
}

// ---- fused dispatch: blocks [0,gemmBlocks) do gemm1, rest do fill_csr ----
__global__ __launch_bounds__(256) void gemm_fill_kernel(const float* __restrict__ X,
                                                        const float* __restrict__ W,
                                                        _Float16* __restrict__ outh,
                                                        float* __restrict__ pout, int nrows,
                                                        int gemmBlocks,
                                                        const int* __restrict__ src,
                                                        const int* __restrict__ dst,
                                                        const unsigned int* __restrict__ bitsG,
                                                        int* __restrict__ rp,
                                                        int* __restrict__ col, int E, int n) {
    __shared__ __align__(16) unsigned char smem[SMEM_BYTES];   // 52.2 KB union
    int b = blockIdx.x;
    if (b < gemmBlocks) {
        gemm_mfma_body(X, W, outh, pout, nrows, b * 64, smem);
    } else {
        fill_csr_body(src, dst, bitsG, rp, col, E, n, b - gemmBlocks, smem);
    }
}

__global__ __launch_bounds__(256) void gemm_f16_dyn_kernel(const float* __restrict__ X,
                                                           const float* __restrict__ W,
                                                           _Float16* __restrict__ outh,
                                                           const int* __restrict__ nrows_p) {
    __shared__ __align__(16) unsigned char smem[SMEM_BYTES];
    int nrows = *nrows_p;
    int rowBase = blockIdx.x * 64;
    if (rowBase >= nrows) return;
    gemm_mfma_body(X, W, outh, nullptr, nrows, rowBase, smem);
}

// ---- layer-1 gather over compact frontier rows (fp16 rows, fp32 accum) ----
__global__ __launch_bounds__(256) void gather_l1_kernel(const _Float16* __restrict__ xwh,
                                                        const float* __restrict__ inv,
                                                        const int* __restrict__ rp,
                                                        const int* __restrict__ col,
                                                        const int* __restrict__ flist,
                                                        const int* __restrict__ nf_p,
                                                        const float* __restrict__ b,
                                                        float* __restrict__ h1c) {
    int ci = blockIdx.x * 4 + (threadIdx.x >> 6);
    if (ci >= *nf_p) return;
    int lane = threadIdx.x & 63;
    int node = flist[ci];
    int start = (node == 0) ? 0 : rp[node - 1];
    int end = rp[node];

    float accx = 0.f, accy = 0.f;
    for (int base = start; base < end; base += 64) {
        int j = base + lane;
        int s_l = 0; float c_l = 0.f;
        if (j < end) { s_l = col[j]; c_l = inv[s_l]; }
        int cnt = min(64, end - base);
        int i = 0;
        for (; i + 4 <= cnt; i += 4) {
            int s0 = __shfl(s_l, i + 0); float f0 = __shfl(c_l, i + 0);
            int s1 = __shfl(s_l, i + 1); float f1 = __shfl(c_l, i + 1);
            int s2 = __shfl(s_l, i + 2); float f2 = __shfl(c_l, i + 2);
            int s3 = __shfl(s_l, i + 3); float f3 = __shfl(c_l, i + 3);
            f16x2 v0 = ((const f16x2*)(xwh + (size_t)s0 * F_DIM))[lane];
            f16x2 v1 = ((const f16x2*)(xwh + (size_t)s1 * F_DIM))[lane];
            f16x2 v2 = ((const f16x2*)(xwh + (size_t)s2 * F_DIM))[lane];
            f16x2 v3 = ((const f16x2*)(xwh + (size_t)s3 * F_DIM))[lane];
            accx += (float)v0[0] * f0 + (float)v1[0] * f1 + (float)v2[0] * f2 + (float)v3[0] * f3;
            accy += (float)v0[1] * f0 + (float)v1[1] * f1 + (float)v2[1] * f2 + (float)v3[1] * f3;
        }
        for (; i < cnt; ++i) {
            int s0 = __shfl(s_l, i); float f0 = __shfl(c_l, i);
            f16x2 v0 = ((const f16x2*)(xwh + (size_t)s0 * F_DIM))[lane];
            accx += (float)v0[0] * f0;
            accy += (float)v0[1] * f0;
        }
    }

    float ivd = inv[node];
    f16x2 self = ((const f16x2*)(xwh + (size_t)node * F_DIM))[lane];
    float vx = accx * ivd + (float)self[0] * ivd * ivd + b[lane * 2];
    float vy = accy * ivd + (float)self[1] * ivd * ivd + b[lane * 2 + 1];
    vx = vx > 0.f ? vx : expf(vx) - 1.f;
    vy = vy > 0.f ? vy : expf(vy) - 1.f;
    ((float2*)(h1c + (size_t)ci * F_DIM))[lane] = make_float2(vx, vy);
}

// ---- layer-2 gather over rows [0,U) (fp16 compact rows) ----
__global__ __launch_bounds__(256) void gather_l2_kernel(const _Float16* __restrict__ xwc,
                                                        const float* __restrict__ inv,
                                                        const int* __restrict__ rp,
                                                        const int* __restrict__ col,
                                                        const int* __restrict__ remap,
                                                        const float* __restrict__ b,
                                                        float* __restrict__ out) {
    int node = blockIdx.x * 4 + (threadIdx.x >> 6);
    if (node >= U_USERS) return;
    int lane = threadIdx.x & 63;
    int start = (node == 0) ? 0 : rp[node - 1];
    int end = rp[node];

    float accx = 0.f, accy = 0.f;
    for (int base = start; base < end; base += 64) {
        int j = base + lane;
        int r_l = 0; float c_l = 0.f;
        if (j < end) { int s = col[j]; c_l = inv[s]; r_l = remap[s]; }
        int cnt = min(64, end - base);
        int i = 0;
        for (; i + 4 <= cnt; i += 4) {
            int r0 = __shfl(r_l, i + 0); float f0 = __shfl(c_l, i + 0);
            int r1 = __shfl(r_l, i + 1); float f1 = __shfl(c_l, i + 1);
            int r2 = __shfl(r_l, i + 2); float f2 = __shfl(c_l, i + 2);
            int r3 = __shfl(r_l, i + 3); float f3 = __shfl(c_l, i + 3);
            f16x2 v0 = ((const f16x2*)(xwc + (size_t)r0 * F_DIM))[lane];
            f16x2 v1 = ((const f16x2*)(xwc + (size_t)r1 * F_DIM))[lane];
            f16x2 v2 = ((const f16x2*)(xwc + (size_t)r2 * F_DIM))[lane];
            f16x2 v3 = ((const f16x2*)(xwc + (size_t)r3 * F_DIM))[lane];
            accx += (float)v0[0] * f0 + (float)v1[0] * f1 + (float)v2[0] * f2 + (float)v3[0] * f3;
            accy += (float)v0[1] * f0 + (float)v1[1] * f1 + (float)v2[1] * f2 + (float)v3[1] * f3;
        }
        for (; i < cnt; ++i) {
            int rr = __shfl(r_l, i); float f0 = __shfl(c_l, i);
            f16x2 v0 = ((const f16x2*)(xwc + (size_t)rr * F_DIM))[lane];
            accx += (float)v0[0] * f0;
            accy += (float)v0[1] * f0;
        }
    }

    float ivd = inv[node];
    f16x2 self = ((const f16x2*)(xwc + (size_t)node * F_DIM))[lane];  // remap[node]==node for node<U
    float vx = accx * ivd + (float)self[0] * ivd * ivd + b[lane * 2];
    float vy = accy * ivd + (float)self[1] * ivd * ivd + b[lane * 2 + 1];
    vx = vx > 0.f ? vx : expf(vx) - 1.f;
    vy = vy > 0.f ? vy : expf(vy) - 1.f;
    ((float2*)(out + (size_t)node * F_DIM))[lane] = make_float2(vx, vy);
}

extern "C" void kernel_launch(void* const* d_in, const int* in_sizes, int n_in,
                              void* d_out, int out_size, void* d_ws, size_t ws_size,
                              hipStream_t stream) {
    const float* x  = (const float*)d_in[0];
    const int*   ei = (const int*)d_in[1];   // [2, E] int32
    const float* W1 = (const float*)d_in[2];
    const float* b1 = (const float*)d_in[3];
    const float* W2 = (const float*)d_in[4];
    const float* b2 = (const float*)d_in[5];
    float* out = (float*)d_out;

    int n = in_sizes[0] / F_DIM;   // 100000
    int E = in_sizes[1] / 2;       // 3200000
    const int* srcI = ei;
    const int* dstI = ei + E;

    // workspace layout (~110 MB)
    _Float16* xwh = (_Float16*)d_ws;                 // n*128 halfs (xw1 / xwc, 25.6MB)
    float* h1c   = (float*)(xwh + (size_t)n * F_DIM);// NFCAP*128 f (24.6MB)
    float* inv   = h1c + (size_t)NFCAP * F_DIM;      // n f
    int* fr      = (int*)(inv + n);                  // n
    int* degF    = fr + n;                           // n
    int* remap   = degF + n;                         // n
    int* rp      = remap + n;                        // n
    int* flist   = rp + n;                           // NFCAP
    int* pA      = flist + NFCAP;                    // 1024
    int* pB      = pA + 1024;                        // 1024
    int* nf_dev  = pB + 1024;                        // 1 (+pad)
    int* col     = nf_dev + 16;                      // E
    unsigned int* partialH = (unsigned int*)(col + E);  // NCHUNK*PSLICE*SW
    unsigned int* bitsG = partialH + (size_t)NCHUNK * PSLICE * SW;  // BMW words

    int nb = (n + SCAN_CHUNK - 1) / SCAN_CHUNK;      // 98

    hipMemsetAsync(fr, 0, (size_t)n * sizeof(int), stream);
    hipMemsetAsync(bitsG, 0, (size_t)BMW * sizeof(unsigned int), stream);

    hist_kernel<<<NCHUNK * PSLICE, 1024, 0, stream>>>(srcI, dstI, partialH, fr, E, n);
    reduce_prep_kernel<<<(NCHUNK * SW + 255) / 256, 256, 0, stream>>>(partialH, inv, fr, degF, bitsG, n);

    scan_reduce2_kernel<<<nb, 256, 0, stream>>>(degF, fr, pA, pB, n);
    scan_partials2_kernel<<<1, 128, 0, stream>>>(pA, pB, nb);
    scan_final2_kernel<<<nb, 256, 0, stream>>>(degF, pA, rp, fr, pB, remap, flist, nf_dev, n);

    // fused: gemm1 (independent MFMA+stream work) overlaps fill_csr's
    // latency-bound scatter. gemm blocks first (shorter job starts early).
    int gemmBlocks = (n + 63) / 64;          // 1563
    int fillBlocks = (E / 4 + 255) / 256;    // 3125
    gemm_fill_kernel<<<gemmBlocks + fillBlocks, 256, 0, stream>>>(
        x, W1, xwh, out, n, gemmBlocks, srcI, dstI, bitsG, rp, col, E, n);

    gather_l1_kernel<<<(NFCAP + 3) / 4, 256, 0, stream>>>(xwh, inv, rp, col, flist, nf_dev, b1, h1c);

    // layer 2: compact MFMA GEMM (nf rows), gather over U rows
    gemm_f16_dyn_kernel<<<(NFCAP + 63) / 64, 256, 0, stream>>>(h1c, W2, xwh, nf_dev);
    gather_l2_kernel<<<(U_USERS + 3) / 4, 256, 0, stream>>>(xwh, inv, rp, col, remap, b2, out);
}